// Round 5
// baseline (76.572 us; speedup 1.0000x reference)
//
#include <hip/hip_runtime.h>

// Quanvolution: 802816 independent 4-qubit sims. Fully wave-synchronous design:
// 64-thread blocks (1 wave) -> 16 independent blocks/CU, no cross-wave barriers.
// Per wave: gates broadcast via v_readlane (SGPRs, no LDS); shared 32x32 f16
// evolution matrix W built redundantly per wave into LDS; per-thread product
// state (layer-1 folded per-wire, fp32) -> f16 k-interleaved (re,im) -> LDS;
// 8x mfma_f32_16x16x32_f16 applies W to 64 patches; |amp|^2 + LDS transpose
// (in-wave, DS in-order) + sign sums. x loads issued first to overlap latency.

typedef _Float16 f16;
typedef _Float16 half8 __attribute__((ext_vector_type(8)));
typedef float f4 __attribute__((ext_vector_type(4)));

#define PK2(a, b) __builtin_bit_cast(float, __builtin_amdgcn_cvt_pkrtz((a), (b)))
#define RDL(x, g) __builtin_bit_cast(float, __builtin_amdgcn_readlane(__builtin_bit_cast(int, (x)), (g)))

__device__ __forceinline__ float2 cmulf(float2 a, float2 b) {
    return make_float2(fmaf(a.x, b.x, -(a.y * b.y)),
                       fmaf(a.x, b.y,   a.y * b.x));
}

__global__ __launch_bounds__(64, 4) void quanv_kernel(
        const float* __restrict__ x,       // (4096, 28, 28)
        const float* __restrict__ params,  // (2, 4, 3)
        float* __restrict__ out)           // (4096, 196*4)
{
    __shared__ __align__(16) f16 Wt[32][40];            // Wt[n][k]=B[k][n], 80B rows
    __shared__ __align__(16) unsigned char SB[64 * 80]; // states (f16) then pr (f32)

    const int l = threadIdx.x;                 // 0..63 == lane
    const int gid = blockIdx.x * 64 + l;       // patch id: n*196 + r*14 + c

    // ---- issue x loads FIRST (consumed much later) ----
    const int n = gid / 196;
    const int p = gid - n * 196;
    const int r = p / 14;
    const int c = p - r * 14;
    const float* xb = x + n * 784 + r * 56 + c * 2;   // even offset -> 8B aligned
    const float2 top = *(const float2*)(xb);
    const float2 bot = *(const float2*)(xb + 28);

    // ---- every lane computes gate (l&7); broadcast to SGPRs via readlane ----
    // U = RX(p2/2) RZ(p1/2) RY(p0/2) = [[a,b],[-conj(b),conj(a)]], a=(gx,gy) b=(gz,gw)
    const float* pg = params + (l & 7) * 3;
    const float ha = 0.5f * pg[0], hb = 0.5f * pg[1], hc = 0.5f * pg[2];
    const float sa = __sinf(ha), ca = __cosf(ha);
    const float sb = __sinf(hb), cb = __cosf(hb);
    const float sc = __sinf(hc), cx = __cosf(hc);
    const float gx = cx*ca*cb + sc*sa*sb;
    const float gy = -(cx*ca*sb + sc*sa*cb);
    const float gz = sc*ca*sb - cx*sa*cb;
    const float gw = cx*sa*sb - sc*ca*cb;
    float Ax[8], Ay[8], Bx[8], By[8];
#pragma unroll
    for (int g = 0; g < 8; ++g) {
        Ax[g] = RDL(gx, g); Ay[g] = RDL(gy, g);
        Bx[g] = RDL(gz, g); By[g] = RDL(gw, g);
    }

    // ---- build W: M = P2*U2*P1 (16x16 complex), 4 entries per lane ----
    // CNOT-ring perm (both layers): idx1=[0,13,3,14,6,11,5,8,12,1,15,2,10,7,9,4]
    const unsigned long long IDX1P = 0x497a2f1c85b6e3d0ULL;
    const unsigned long long INV1P = 0xa3185ce7d46f2b90ULL;
    const int mE = l & 15;
    const int kN = (int)((INV1P >> (mE * 4)) & 15);
#pragma unroll
    for (int ii = 0; ii < 4; ++ii) {
        const int iE = (l >> 4) + 4 * ii;
        const int jN = (int)((IDX1P >> (iE * 4)) & 15);
        float2 e = make_float2(1.f, 0.f);
#pragma unroll
        for (int w = 0; w < 4; ++w) {
            const int jb = (jN >> (3 - w)) & 1;
            const int kb = (kN >> (3 - w)) & 1;
            // u[0][0]=(ax,ay) u[0][1]=(bx,by) u[1][0]=(-bx,by) u[1][1]=(ax,-ay)
            const float ux = jb ? (kb ?  Ax[4+w] : -Bx[4+w]) : (kb ? Bx[4+w] : Ax[4+w]);
            const float uy = jb ? (kb ? -Ay[4+w] :  By[4+w]) : (kb ? By[4+w] : Ay[4+w]);
            e = cmulf(e, make_float2(ux, uy));
        }
        // k-interleaved rows: B[2m][i]=Re, B[2m+1][i]=-Im ; B[2m][16+i]=Im, B[2m+1][16+i]=Re
        *(float*)&Wt[iE][2 * mE]      = PK2(e.x, -e.y);
        *(float*)&Wt[16 + iE][2 * mE] = PK2(e.y,  e.x);
    }

    // ---- per-patch product state: RY(pixel)|0> then layer-1 gate, per wire ----
    const float pw0 = 0.5f * top.x, pw1 = 0.5f * top.y;
    const float pw2 = 0.5f * bot.x, pw3 = 0.5f * bot.y;
    const float pwv[4] = {pw0, pw1, pw2, pw3};
    float2 wv[4][2];
#pragma unroll
    for (int w = 0; w < 4; ++w) {
        const float cw = __cosf(pwv[w]);
        const float sw = __sinf(pwv[w]);
        wv[w][0] = make_float2(fmaf(Bx[w], sw,  Ax[w] * cw), fmaf( By[w], sw, Ay[w] * cw));
        wv[w][1] = make_float2(fmaf(Ax[w], sw, -Bx[w] * cw), fmaf(-Ay[w], sw, By[w] * cw));
    }

    float2 ab[4], cd[4];
#pragma unroll
    for (int i = 0; i < 2; ++i)
#pragma unroll
        for (int j = 0; j < 2; ++j) {
            ab[i * 2 + j] = cmulf(wv[0][i], wv[1][j]);
            cd[i * 2 + j] = cmulf(wv[2][i], wv[3][j]);
        }
    // s[a*8+b*4+c*2+d]; pack k-interleaved: dword d = (re_d, im_d)
    float sd[16];
#pragma unroll
    for (int hi = 0; hi < 4; ++hi)
#pragma unroll
        for (int lo = 0; lo < 4; ++lo) {
            const float2 sv = cmulf(ab[hi], cd[lo]);
            sd[hi * 4 + lo] = PK2(sv.x, sv.y);
        }

    f16* st = (f16*)(SB + l * 80);
    *(float4*)(st)      = make_float4(sd[0],  sd[1],  sd[2],  sd[3]);
    *(float4*)(st + 8)  = make_float4(sd[4],  sd[5],  sd[6],  sd[7]);
    *(float4*)(st + 16) = make_float4(sd[8],  sd[9],  sd[10], sd[11]);
    *(float4*)(st + 24) = make_float4(sd[12], sd[13], sd[14], sd[15]);

    __syncthreads();   // single wave: near-free; guards Wt + SB for frag reads

    // ---- MFMA: D[patch][n] = sum_k state[patch][k] * B[k][n] ----
    const int q = l >> 4, c16 = l & 15;
    const half8 b0 = *(const half8*)&Wt[c16][q * 8];        // cols 0..15  (re out)
    const half8 b1 = *(const half8*)&Wt[16 + c16][q * 8];   // cols 16..31 (im out)
    const f4 zf4 = {0.f, 0.f, 0.f, 0.f};
    f4 d0[4], d1[4];
#pragma unroll
    for (int m = 0; m < 4; ++m) {
        const half8 am = *(const half8*)(SB + (m * 16 + c16) * 80 + q * 16);
        d0[m] = __builtin_amdgcn_mfma_f32_16x16x32_f16(am, b0, zf4, 0, 0, 0);
        d1[m] = __builtin_amdgcn_mfma_f32_16x16x32_f16(am, b1, zf4, 0, 0, 0);
    }

    // ---- |amp|^2 transpose via LDS (in-wave, DS in-order; verified R4) ----
    // C/D layout: col=lane&15 (amp), row=quad*4+reg -> patch_local = m*16+q*4+reg
    float* prb = (float*)SB;   // reuse: [64 patches][20 floats]
#pragma unroll
    for (int m = 0; m < 4; ++m)
#pragma unroll
        for (int reg = 0; reg < 4; ++reg) {
            const float pv = fmaf(d0[m][reg], d0[m][reg], d1[m][reg] * d1[m][reg]);
            prb[(m * 16 + q * 4 + reg) * 20 + c16] = pv;   // 2-way banks: free
        }

    const float4 p0 = *(const float4*)(prb + l * 20);
    const float4 p1 = *(const float4*)(prb + l * 20 + 4);
    const float4 p2 = *(const float4*)(prb + l * 20 + 8);
    const float4 p3 = *(const float4*)(prb + l * 20 + 12);

    // <Z_w>: amp i = a*8+b*4+c*2+d, wire0=a ... wire3=d
    const float t00 = p0.x + p0.y + p0.z + p0.w;
    const float t01 = p1.x + p1.y + p1.z + p1.w;
    const float t10 = p2.x + p2.y + p2.z + p2.w;
    const float t11 = p3.x + p3.y + p3.z + p3.w;
    const float e0 = (t00 + t01) - (t10 + t11);
    const float e1 = (t00 - t01) + (t10 - t11);

    const float u00 = p0.x + p1.x + p2.x + p3.x;
    const float u01 = p0.y + p1.y + p2.y + p3.y;
    const float u10 = p0.z + p1.z + p2.z + p3.z;
    const float u11 = p0.w + p1.w + p2.w + p3.w;
    const float e2 = (u00 + u01) - (u10 + u11);
    const float e3 = (u00 - u01) + (u10 - u11);

    *(float4*)(out + gid * 4) = make_float4(e0, e1, e2, e3);
}

extern "C" void kernel_launch(void* const* d_in, const int* in_sizes, int n_in,
                              void* d_out, int out_size, void* d_ws, size_t ws_size,
                              hipStream_t stream) {
    const float* x      = (const float*)d_in[0];   // 4096*28*28
    const float* params = (const float*)d_in[1];   // 2*4*3
    float* out = (float*)d_out;                    // 4096*784

    const int npatch = 4096 * 196;                 // 802816 = 12544 * 64
    quanv_kernel<<<npatch / 64, 64, 0, stream>>>(x, params, out);
}

// Round 6
// 71.626 us; speedup vs baseline: 1.0691x; 1.0691x over previous
//
#include <hip/hip_runtime.h>

// Quanvolution: 802816 independent 4-qubit sims. R6 = R4 block structure (256
// threads, W-build spread 1 entry/thread, gates via LDS) + R5's verified
// k-interleaved W/state packing + x-loads hoisted to the top of the kernel.
// Evolution after the product state is one shared 16x16 complex matrix
// M = P2*(u4..u7)*P1 -> real 32x32 f16 W, applied by 8 mfma_f32_16x16x32_f16
// per wave (64 patches). Epilogue: |amp|^2, in-wave LDS transpose, sign sums.

typedef _Float16 f16;
typedef _Float16 half8 __attribute__((ext_vector_type(8)));
typedef float f4 __attribute__((ext_vector_type(4)));

#define PK2(a, b) __builtin_bit_cast(float, __builtin_amdgcn_cvt_pkrtz((a), (b)))

__device__ __forceinline__ float2 cmulf(float2 a, float2 b) {
    return make_float2(fmaf(a.x, b.x, -(a.y * b.y)),
                       fmaf(a.x, b.y,   a.y * b.x));
}

__global__ __launch_bounds__(256, 4) void quanv_kernel(
        const float* __restrict__ x,       // (4096, 28, 28)
        const float* __restrict__ params,  // (2, 4, 3)
        float* __restrict__ out)           // (4096, 196*4)
{
    __shared__ float4 Gs[8];                            // SU(2) gates {ax,ay,bx,by}
    __shared__ __align__(16) f16 Wt[32][40];            // Wt[n][k]=B[k][n], 80B rows
    __shared__ __align__(16) unsigned char SB[4][5120]; // per-wave: states then pr

    const int t = threadIdx.x;
    const int gid = blockIdx.x * 256 + t;      // patch id: n*196 + r*14 + c

    // ---- x loads FIRST: ~900cyc cold-HBM latency hides behind gate+W build ----
    const int n = gid / 196;
    const int p = gid - n * 196;
    const int r = p / 14;
    const int c = p - r * 14;
    const float* xb = x + n * 784 + r * 56 + c * 2;   // even offset -> 8B aligned
    const float2 top = *(const float2*)(xb);
    const float2 bot = *(const float2*)(xb + 28);

    // ---- gates: U = RX(p2/2) RZ(p1/2) RY(p0/2) = [[a,b],[-conj(b),conj(a)]] ----
    if (t < 8) {
        const float* pg = params + t * 3;
        const float ha = 0.5f * pg[0], hb = 0.5f * pg[1], hc = 0.5f * pg[2];
        const float sa = __sinf(ha), ca = __cosf(ha);
        const float sb = __sinf(hb), cb = __cosf(hb);
        const float sc = __sinf(hc), cx = __cosf(hc);
        Gs[t] = make_float4(cx*ca*cb + sc*sa*sb,      // ax
                            -(cx*ca*sb + sc*sa*cb),   // ay
                            sc*ca*sb - cx*sa*cb,      // bx
                            cx*sa*sb - sc*ca*cb);     // by
    }
    __syncthreads();

    // ---- W-build: M = P2*U2*P1, one complex entry per thread ----
    // CNOT-ring perm (both layers): idx1=[0,13,3,14,6,11,5,8,12,1,15,2,10,7,9,4]
    {
        const unsigned long long IDX1P = 0x497a2f1c85b6e3d0ULL;
        const unsigned long long INV1P = 0xa3185ce7d46f2b90ULL;
        const int iE = t >> 4;                           // output amp
        const int mE = t & 15;                           // input amp
        const int jN = (int)((IDX1P >> (iE * 4)) & 15);  // row into U2
        const int kN = (int)((INV1P >> (mE * 4)) & 15);  // col into U2
        float2 e = make_float2(1.f, 0.f);
#pragma unroll
        for (int w = 0; w < 4; ++w) {
            const float4 g = Gs[4 + w];
            const int jb = (jN >> (3 - w)) & 1;
            const int kb = (kN >> (3 - w)) & 1;
            // u[0][0]=(ax,ay) u[0][1]=(bx,by) u[1][0]=(-bx,by) u[1][1]=(ax,-ay)
            const float ux = jb ? (kb ?  g.x : -g.z) : (kb ? g.z : g.x);
            const float uy = jb ? (kb ? -g.y :  g.w) : (kb ? g.w : g.y);
            e = cmulf(e, make_float2(ux, uy));
        }
        // k-interleaved: B[2m][i]=Re, B[2m+1][i]=-Im ; B[2m][16+i]=Im, B[2m+1][16+i]=Re
        *(float*)&Wt[iE][2 * mE]      = PK2(e.x, -e.y);
        *(float*)&Wt[16 + iE][2 * mE] = PK2(e.y,  e.x);
    }

    // ---- per-patch product state: RY(pixel)|0> then layer-1 gate, per wire ----
    const float pwv[4] = {0.5f * top.x, 0.5f * top.y, 0.5f * bot.x, 0.5f * bot.y};
    float2 wv[4][2];
#pragma unroll
    for (int w = 0; w < 4; ++w) {
        const float cw = __cosf(pwv[w]);
        const float sw = __sinf(pwv[w]);
        const float4 g = Gs[w];
        wv[w][0] = make_float2(fmaf(g.z, sw,  g.x * cw), fmaf( g.w, sw, g.y * cw));
        wv[w][1] = make_float2(fmaf(g.x, sw, -g.z * cw), fmaf(-g.y, sw, g.w * cw));
    }

    float2 ab[4], cd[4];
#pragma unroll
    for (int i = 0; i < 2; ++i)
#pragma unroll
        for (int j = 0; j < 2; ++j) {
            ab[i * 2 + j] = cmulf(wv[0][i], wv[1][j]);
            cd[i * 2 + j] = cmulf(wv[2][i], wv[3][j]);
        }
    // s[a*8+b*4+c*2+d], packed k-interleaved: dword d = (re_d, im_d)
    float sd[16];
#pragma unroll
    for (int hi = 0; hi < 4; ++hi)
#pragma unroll
        for (int lo = 0; lo < 4; ++lo) {
            const float2 sv = cmulf(ab[hi], cd[lo]);
            sd[hi * 4 + lo] = PK2(sv.x, sv.y);
        }

    const int l   = t & 63;          // lane
    const int wid = t >> 6;          // wave id
    const int q   = l >> 4;          // quad
    const int c16 = l & 15;

    f16* st = (f16*)(SB[wid] + l * 80);
    *(float4*)(st)      = make_float4(sd[0],  sd[1],  sd[2],  sd[3]);
    *(float4*)(st + 8)  = make_float4(sd[4],  sd[5],  sd[6],  sd[7]);
    *(float4*)(st + 16) = make_float4(sd[8],  sd[9],  sd[10], sd[11]);
    *(float4*)(st + 24) = make_float4(sd[12], sd[13], sd[14], sd[15]);

    __syncthreads();   // Wt ready (state region is per-wave)

    // ---- MFMA: D[patch][n] = sum_k state[patch][k] * B[k][n] ----
    const half8 b0 = *(const half8*)&Wt[c16][q * 8];        // cols 0..15  (re out)
    const half8 b1 = *(const half8*)&Wt[16 + c16][q * 8];   // cols 16..31 (im out)
    const f4 zf4 = {0.f, 0.f, 0.f, 0.f};
    f4 d0[4], d1[4];
#pragma unroll
    for (int m = 0; m < 4; ++m) {
        const half8 am = *(const half8*)(SB[wid] + (m * 16 + c16) * 80 + q * 16);
        d0[m] = __builtin_amdgcn_mfma_f32_16x16x32_f16(am, b0, zf4, 0, 0, 0);
        d1[m] = __builtin_amdgcn_mfma_f32_16x16x32_f16(am, b1, zf4, 0, 0, 0);
    }

    // ---- |amp|^2 transpose via LDS (in-wave, DS in-order; verified R4/R5) ----
    // C/D layout: col=lane&15 (amp), row=quad*4+reg -> patch_local = m*16+q*4+reg
    float* prb = (float*)SB[wid];   // reuse: [64 patches][20 floats]
#pragma unroll
    for (int m = 0; m < 4; ++m)
#pragma unroll
        for (int reg = 0; reg < 4; ++reg) {
            const float pv = fmaf(d0[m][reg], d0[m][reg], d1[m][reg] * d1[m][reg]);
            prb[(m * 16 + q * 4 + reg) * 20 + c16] = pv;   // 2-way banks: free
        }

    const float4 p0 = *(const float4*)(prb + l * 20);
    const float4 p1 = *(const float4*)(prb + l * 20 + 4);
    const float4 p2 = *(const float4*)(prb + l * 20 + 8);
    const float4 p3 = *(const float4*)(prb + l * 20 + 12);

    // <Z_w>: amp i = a*8+b*4+c*2+d, wire0=a ... wire3=d
    const float t00 = p0.x + p0.y + p0.z + p0.w;
    const float t01 = p1.x + p1.y + p1.z + p1.w;
    const float t10 = p2.x + p2.y + p2.z + p2.w;
    const float t11 = p3.x + p3.y + p3.z + p3.w;
    const float e0 = (t00 + t01) - (t10 + t11);
    const float e1 = (t00 - t01) + (t10 - t11);

    const float u00 = p0.x + p1.x + p2.x + p3.x;
    const float u01 = p0.y + p1.y + p2.y + p3.y;
    const float u10 = p0.z + p1.z + p2.z + p3.z;
    const float u11 = p0.w + p1.w + p2.w + p3.w;
    const float e2 = (u00 + u01) - (u10 + u11);
    const float e3 = (u00 - u01) + (u10 - u11);

    *(float4*)(out + gid * 4) = make_float4(e0, e1, e2, e3);
}

extern "C" void kernel_launch(void* const* d_in, const int* in_sizes, int n_in,
                              void* d_out, int out_size, void* d_ws, size_t ws_size,
                              hipStream_t stream) {
    const float* x      = (const float*)d_in[0];   // 4096*28*28
    const float* params = (const float*)d_in[1];   // 2*4*3
    float* out = (float*)d_out;                    // 4096*784

    const int npatch = 4096 * 196;                 // 802816, divisible by 256
    quanv_kernel<<<npatch / 256, 256, 0, stream>>>(x, params, out);
}